// Round 5
// baseline (150.893 us; speedup 1.0000x reference)
//
#include <hip/hip_runtime.h>
#include <math.h>

// ---------------- problem constants ----------------
#define B_TOT 8192
#define KE 400      // 16 nodes * 25 t (ecc K)
#define KR 300      // 12 nodes * 25 t (err K)
#define MEP 416     // ecc K padded to 13*32
#define MRP 320     // err K padded to 10*32
#define ROWS 16     // batch rows per block (R4: 32 -> 16 for 2x grid)

// LDS strides (bf16 elements), padded for bank-conflict avoidance
#define SXE_LD 424
#define SXR_LD 328
#define SEH_LD 72

// ---------------- workspace layout ----------------
// float offsets
#define OFF_WEFF0E 0
#define OFF_WEFF1E 1600
#define OFF_WEFF0R 3200
#define OFF_WEFF1R 4800
#define OFF_CVE    6400
#define OFF_CVR    6464
#define OFF_BE     6528
#define OFF_BR     6784
// ushort offsets (from d_ws base viewed as ushort*), 16B-aligned
#define U_AET 14080                   // AwT_ecc [256][416] bf16
#define U_ART (U_AET + 256 * MEP)     // AwT_err [256][320] bf16
#define U_WET (U_ART + 256 * MRP)     // WeT     [64][64]  bf16

typedef __attribute__((ext_vector_type(8))) short short8;
typedef __attribute__((ext_vector_type(4))) float floatx4;

__device__ __forceinline__ float sigmoidf_(float x) { return 1.f / (1.f + __expf(-x)); }
__device__ __forceinline__ float tanhf_(float x) { float e = __expf(2.f * x); return (e - 1.f) / (e + 1.f); }
__device__ __forceinline__ unsigned short f2bf(float x) {
    unsigned u = __float_as_uint(x);
    u += 0x7fffu + ((u >> 16) & 1u);          // round-to-nearest-even
    return (unsigned short)(u >> 16);
}

// =====================================================================
// Kernel 1: fold Conv1d into W0/W1 -> Weff [25][64] per (branch, order),
// cvec[64] = b + sum_ct bt[c]*(W0-W1)[ct]  (ring row-sum of L_hat = -1),
// and zero the bias accumulators (fold_graph atomicAdds into them).
// grid = 103 blocks x 256 threads
// =====================================================================
__global__ __launch_bounds__(256) void fold_temporal(
    const float* __restrict__ wt_ecc, const float* __restrict__ bt_ecc,
    const float* __restrict__ wt_err, const float* __restrict__ bt_err,
    const float* __restrict__ W0_ecc, const float* __restrict__ W1_ecc, const float* __restrict__ b_ecc,
    const float* __restrict__ W0_err, const float* __restrict__ W1_err, const float* __restrict__ b_err,
    float* __restrict__ ws)
{
    const int blk = blockIdx.x;
    const int tid = threadIdx.x;
    const int cq = tid >> 6;    // 0..3  (c-chunk of 8)
    const int g  = tid & 63;

    __shared__ float red[4][64];

    if (blk < 100) {
        const int m = blk / 25;       // 0: W0_ecc, 1: W1_ecc, 2: W0_err, 3: W1_err
        const int tin = blk % 25;
        const bool is_err = (m >= 2);
        const float* wt = is_err ? wt_err : wt_ecc;
        const float* W = (m & 1) ? (is_err ? W1_err : W1_ecc) : (is_err ? W0_err : W0_ecc);
        const int t0 = tin > 0 ? tin - 1 : 0;
        const int t1 = tin < 24 ? tin + 1 : 24;
        float s = 0.f;
        #pragma unroll
        for (int c8 = 0; c8 < 8; ++c8) {
            const int c = cq * 8 + c8;
            for (int t = t0; t <= t1; ++t) {
                const int k = tin - t + 1;           // 0..2
                s = fmaf(wt[c * 3 + k], W[(c * 25 + t) * 64 + g], s);
            }
        }
        red[cq][g] = s;
        __syncthreads();
        if (tid < 64)
            ws[m * 1600 + tin * 64 + g] = red[0][g] + red[1][g] + red[2][g] + red[3][g];
    } else if (blk < 102) {
        const bool is_err = (blk == 101);
        const float* bt = is_err ? bt_err : bt_ecc;
        const float* W0 = is_err ? W0_err : W0_ecc;
        const float* W1 = is_err ? W1_err : W1_ecc;
        const float* bb = is_err ? b_err : b_ecc;
        float s = 0.f;
        #pragma unroll
        for (int c8 = 0; c8 < 8; ++c8) {
            const int c = cq * 8 + c8;
            const float btc = bt[c];
            #pragma unroll
            for (int t = 0; t < 25; ++t) {
                const int ct = (c * 25 + t) * 64 + g;
                s = fmaf(btc, W0[ct] - W1[ct], s);
            }
        }
        red[cq][g] = s;
        __syncthreads();
        if (tid < 64)
            ws[(is_err ? OFF_CVR : OFF_CVE) + g] =
                bb[g] + red[0][g] + red[1][g] + red[2][g] + red[3][g];
    } else {
        // zero bias accumulators for fold_graph's atomicAdd
        ws[OFF_BE + tid] = 0.f;
        ws[OFF_BR + tid] = 0.f;
    }
}

// =====================================================================
// Kernel 2: fold Weff + ring stencil + Wp -> AwT (bf16, transposed, padded),
// biases (fp32, 16-way split + atomicAdd), WeT (bf16 transpose of We).
// grid = 416 + 320 + 16 + 16 + 1 = 769 blocks x 256 threads
// =====================================================================
__global__ __launch_bounds__(256) void fold_graph(
    const float* __restrict__ Wp_ecc, const float* __restrict__ bp_ecc,
    const float* __restrict__ Wp_err, const float* __restrict__ bp_err,
    const float* __restrict__ We,
    float* __restrict__ wsf, unsigned short* __restrict__ wsu)
{
    const int blk = blockIdx.x;
    const int h = threadIdx.x;

    if (blk < MEP) {
        const int k = blk;
        float s = 0.f;
        if (k < KE) {
            const int v = k / 25, tin = k % 25;
            const int vp = (v + 1) & 15, vm = (v + 15) & 15;
            const float* w0 = wsf + OFF_WEFF0E + tin * 64;
        const float* w1 = wsf + OFF_WEFF1E + tin * 64;
            #pragma unroll 4
            for (int g = 0; g < 64; ++g) {
                s = fmaf(w0[g], Wp_ecc[(v * 64 + g) * 256 + h], s);
                s = fmaf(-0.5f * w1[g], Wp_ecc[(vp * 64 + g) * 256 + h] + Wp_ecc[(vm * 64 + g) * 256 + h], s);
            }
        }
        wsu[U_AET + (size_t)h * MEP + k] = f2bf(s);
    } else if (blk < MEP + MRP) {
        const int k = blk - MEP;
        float s = 0.f;
        if (k < KR) {
            const int v = k / 25, tin = k % 25;
            const int vp = (v + 1) % 12, vm = (v + 11) % 12;
            const float* w0 = wsf + OFF_WEFF0R + tin * 64;
            const float* w1 = wsf + OFF_WEFF1R + tin * 64;
            #pragma unroll 4
            for (int g = 0; g < 64; ++g) {
                s = fmaf(w0[g], Wp_err[(v * 64 + g) * 256 + h], s);
                s = fmaf(-0.5f * w1[g], Wp_err[(vp * 64 + g) * 256 + h] + Wp_err[(vm * 64 + g) * 256 + h], s);
            }
        }
        wsu[U_ART + (size_t)h * MRP + k] = f2bf(s);
    } else if (blk < MEP + MRP + 16) {
        // bias_ecc: 1024 (v,g) terms split into 16 chunks of 64
        const int i = blk - (MEP + MRP);
        const float* cv = wsf + OFF_CVE;
        float s = (i == 0) ? bp_ecc[h] : 0.f;
        #pragma unroll 4
        for (int jj = 0; jj < 64; ++jj) {
            const int j = i * 64 + jj;
            s = fmaf(cv[j & 63], Wp_ecc[(size_t)j * 256 + h], s);
        }
        atomicAdd(&wsf[OFF_BE + h], s);
    } else if (blk < MEP + MRP + 32) {
        // bias_err: 768 terms, 12 active chunks
        const int i = blk - (MEP + MRP + 16);
        const float* cv = wsf + OFF_CVR;
        float s = (i == 0) ? bp_err[h] : 0.f;
        if (i < 12) {
            #pragma unroll 4
            for (int jj = 0; jj < 64; ++jj) {
                const int j = i * 64 + jj;
                s = fmaf(cv[j & 63], Wp_err[(size_t)j * 256 + h], s);
            }
        }
        atomicAdd(&wsf[OFF_BR + h], s);
    } else {
        // WeT[e][d] = We[d][e], bf16
        for (int it = 0; it < 16; ++it) {
            const int idx = it * 256 + h;
            const int e = idx >> 6, d = idx & 63;
            wsu[U_WET + e * 64 + d] = f2bf(We[d * 64 + e]);
        }
    }
}

// =====================================================================
// Kernel 3 (fused): per-block 16 batch rows, 4 waves (one 64-col slab each).
// grid = 512 blocks; LDS 26.4 KB -> >=4 blocks/CU (16 waves/CU) for latency
// hiding of the per-kc L2 B-fragment loads.  Epilogue in registers + shfl.
// =====================================================================
__global__ __launch_bounds__(256, 4) void fused_main(
    const float* __restrict__ ecc, const float* __restrict__ err, const float* __restrict__ ehr,
    const float* __restrict__ wsf, const unsigned short* __restrict__ wsu,
    const float* __restrict__ Wa, const float* __restrict__ ba,
    const float* __restrict__ be_, const float* __restrict__ Wf2, const float* __restrict__ bf2,
    float* __restrict__ out)
{
    const unsigned short* awt_e = wsu + U_AET;
    const unsigned short* awt_r = wsu + U_ART;
    const unsigned short* wet   = wsu + U_WET;
    const float* biasE = wsf + OFF_BE;
    const float* biasR = wsf + OFF_BR;

    __shared__ __align__(16) char smem[ROWS * (SXE_LD + SXR_LD + SEH_LD) * 2];
    unsigned short* sxe = (unsigned short*)smem;          // [16][SXE_LD]
    unsigned short* sxr = sxe + ROWS * SXE_LD;            // [16][SXR_LD]
    unsigned short* seh = sxr + ROWS * SXR_LD;            // [16][SEH_LD]
    // epilogue scratch overlays sxe (used only after the post-MFMA barrier)
    float* pa_part = (float*)smem;                        // [4][16]
    float* at_arr  = pa_part + 64;                        // [16]
    float* po_part = at_arr + 16;                         // [4][16]

    const int tid = threadIdx.x;
    const int row0 = blockIdx.x * ROWS;

    // ---- stage X_ecc: 16 rows x 106 quads (real quads < 100) ----
    for (int it = 0; it < 7; ++it) {
        const int f = it * 256 + tid;
        if (f < ROWS * 106) {
            const int r = f / 106, q = f - r * 106;
            float4 v = make_float4(0.f, 0.f, 0.f, 0.f);
            if (q < 100) v = *(const float4*)(ecc + (size_t)(row0 + r) * KE + q * 4);
            const unsigned p0 = (unsigned)f2bf(v.x) | ((unsigned)f2bf(v.y) << 16);
            const unsigned p1 = (unsigned)f2bf(v.z) | ((unsigned)f2bf(v.w) << 16);
            *(uint2*)&sxe[r * SXE_LD + q * 4] = make_uint2(p0, p1);
        }
    }
    // ---- stage X_err: 16 rows x 82 quads (real quads < 75) ----
    for (int it = 0; it < 6; ++it) {
        const int f = it * 256 + tid;
        if (f < ROWS * 82) {
            const int r = f / 82, q = f - r * 82;
            float4 v = make_float4(0.f, 0.f, 0.f, 0.f);
            if (q < 75) v = *(const float4*)(err + (size_t)(row0 + r) * KR + q * 4);
            const unsigned p0 = (unsigned)f2bf(v.x) | ((unsigned)f2bf(v.y) << 16);
            const unsigned p1 = (unsigned)f2bf(v.z) | ((unsigned)f2bf(v.w) << 16);
            *(uint2*)&sxr[r * SXR_LD + q * 4] = make_uint2(p0, p1);
        }
    }
    // ---- stage ehr: 16 rows x 16 quads exactly (256 entries) ----
    {
        const int r = tid >> 4, q = tid & 15;
        const float4 v = *(const float4*)(ehr + (size_t)(row0 + r) * 64 + q * 4);
        const unsigned p0 = (unsigned)f2bf(v.x) | ((unsigned)f2bf(v.y) << 16);
        const unsigned p1 = (unsigned)f2bf(v.z) | ((unsigned)f2bf(v.w) << 16);
        *(uint2*)&seh[r * SEH_LD + q * 4] = make_uint2(p0, p1);
    }
    __syncthreads();

    const int wv = tid >> 6, lane = tid & 63;
    const int lm = lane & 15, lq = lane >> 4;
    const int n0 = wv * 64;

    floatx4 accE[4], accR[4], accH;
    accH = (floatx4){0.f, 0.f, 0.f, 0.f};
    #pragma unroll
    for (int nt = 0; nt < 4; ++nt) {
        accE[nt] = (floatx4){0.f, 0.f, 0.f, 0.f};
        accR[nt] = (floatx4){0.f, 0.f, 0.f, 0.f};
    }

    // ---- ehr_p = ehr @ We : wave handles e-slab wv (e = 16*wv + lm) ----
    #pragma unroll
    for (int kc = 0; kc < 2; ++kc) {
        const short8 b = *(const short8*)(wet + (wv * 16 + lm) * 64 + kc * 32 + lq * 8);
        const short8 a = *(const short8*)&seh[lm * SEH_LD + kc * 32 + lq * 8];
        accH = __builtin_amdgcn_mfma_f32_16x16x32_bf16(a, b, accH, 0, 0, 0);
    }
    // ---- ecc branch: 13 k-chunks ----
    #pragma unroll
    for (int kc = 0; kc < 13; ++kc) {
        const short8 a0 = *(const short8*)&sxe[lm * SXE_LD + kc * 32 + lq * 8];
        #pragma unroll
        for (int nt = 0; nt < 4; ++nt) {
            const short8 b = *(const short8*)(awt_e + (size_t)(n0 + nt * 16 + lm) * MEP + kc * 32 + lq * 8);
            accE[nt] = __builtin_amdgcn_mfma_f32_16x16x32_bf16(a0, b, accE[nt], 0, 0, 0);
        }
    }
    // ---- err branch: 10 k-chunks ----
    #pragma unroll
    for (int kc = 0; kc < 10; ++kc) {
        const short8 a0 = *(const short8*)&sxr[lm * SXR_LD + kc * 32 + lq * 8];
        #pragma unroll
        for (int nt = 0; nt < 4; ++nt) {
            const short8 b = *(const short8*)(awt_r + (size_t)(n0 + nt * 16 + lm) * MRP + kc * 32 + lq * 8);
            accR[nt] = __builtin_amdgcn_mfma_f32_16x16x32_bf16(a0, b, accR[nt], 0, 0, 0);
        }
    }

    // ---- per-lane epilogue constants (L2-hot scalar loads) ----
    float bE[4], bR[4], wa[4], wf[4];
    #pragma unroll
    for (int nt = 0; nt < 4; ++nt) {
        const int h = n0 + nt * 16 + lm;
        bE[nt] = biasE[h]; bR[nt] = biasR[h]; wa[nt] = Wa[h]; wf[nt] = Wf2[h];
    }
    const int e_lane = wv * 16 + lm;
    const float eh_be = be_[e_lane];
    const float eh_wf = Wf2[256 + e_lane];

    // ---- pass 1: attention logits, pure register + shfl ----
    float pa_lane[4];
    #pragma unroll
    for (int rg = 0; rg < 4; ++rg) {
        float s = 0.f;
        #pragma unroll
        for (int nt = 0; nt < 4; ++nt) {
            const float ev = accE[nt][rg] + bE[nt];
            const float rv = accR[nt][rg] + bR[nt];
            s = fmaf(tanhf_(ev + rv), wa[nt], s);
        }
        s += __shfl_xor(s, 1, 64); s += __shfl_xor(s, 2, 64);
        s += __shfl_xor(s, 4, 64); s += __shfl_xor(s, 8, 64);
        pa_lane[rg] = s;
    }

    __syncthreads();   // all staging-LDS reads complete; safe to overlay scratch
    if (lm == 0) {
        #pragma unroll
        for (int rg = 0; rg < 4; ++rg)
            pa_part[wv * 16 + lq * 4 + rg] = pa_lane[rg];
    }
    __syncthreads();
    if (tid < 16)
        at_arr[tid] = sigmoidf_(pa_part[tid] + pa_part[16 + tid] + pa_part[32 + tid] + pa_part[48 + tid] + ba[0]);
    __syncthreads();

    // ---- pass 2: fused + EHR dot with Wf2, register + shfl ----
    float po_lane[4];
    #pragma unroll
    for (int rg = 0; rg < 4; ++rg) {
        const int r = lq * 4 + rg;
        const float at = at_arr[r];
        const float om = 1.f - at;
        float s = 0.f;
        #pragma unroll
        for (int nt = 0; nt < 4; ++nt) {
            const float ev = accE[nt][rg] + bE[nt];
            const float rv = accR[nt][rg] + bR[nt];
            s = fmaf(fmaxf(at * ev + om * rv, 0.f), wf[nt], s);
        }
        s = fmaf(fmaxf(accH[rg] + eh_be, 0.f), eh_wf, s);
        s += __shfl_xor(s, 1, 64); s += __shfl_xor(s, 2, 64);
        s += __shfl_xor(s, 4, 64); s += __shfl_xor(s, 8, 64);
        po_lane[rg] = s;
    }
    if (lm == 0) {
        #pragma unroll
        for (int rg = 0; rg < 4; ++rg)
            po_part[wv * 16 + lq * 4 + rg] = po_lane[rg];
    }
    __syncthreads();
    if (tid < 16)
        out[row0 + tid] = sigmoidf_(po_part[tid] + po_part[16 + tid] + po_part[32 + tid] + po_part[48 + tid] + bf2[0]);
}

// =====================================================================
extern "C" void kernel_launch(void* const* d_in, const int* in_sizes, int n_in,
                              void* d_out, int out_size, void* d_ws, size_t ws_size,
                              hipStream_t stream)
{
    (void)in_sizes; (void)n_in; (void)out_size; (void)ws_size;
    const float* ecc    = (const float*)d_in[0];
    const float* err    = (const float*)d_in[1];
    const float* ehr    = (const float*)d_in[2];
    const float* wt_ecc = (const float*)d_in[3];
    const float* bt_ecc = (const float*)d_in[4];
    const float* wt_err = (const float*)d_in[5];
    const float* bt_err = (const float*)d_in[6];
    const float* W0_ecc = (const float*)d_in[7];
    const float* W1_ecc = (const float*)d_in[8];
    const float* b_ecc  = (const float*)d_in[9];
    const float* W0_err = (const float*)d_in[10];
    const float* W1_err = (const float*)d_in[11];
    const float* b_err  = (const float*)d_in[12];
    const float* Wp_ecc = (const float*)d_in[13];
    const float* bp_ecc = (const float*)d_in[14];
    const float* Wp_err = (const float*)d_in[15];
    const float* bp_err = (const float*)d_in[16];
    const float* Wa     = (const float*)d_in[17];
    const float* ba     = (const float*)d_in[18];
    const float* We     = (const float*)d_in[19];
    const float* be     = (const float*)d_in[20];
    const float* Wf2    = (const float*)d_in[21];
    const float* bf2    = (const float*)d_in[22];
    float* wsf = (float*)d_ws;
    unsigned short* wsu = (unsigned short*)d_ws;
    float* out = (float*)d_out;

    fold_temporal<<<dim3(103), dim3(256), 0, stream>>>(
        wt_ecc, bt_ecc, wt_err, bt_err, W0_ecc, W1_ecc, b_ecc, W0_err, W1_err, b_err, wsf);
    fold_graph<<<dim3(MEP + MRP + 32 + 1), dim3(256), 0, stream>>>(
        Wp_ecc, bp_ecc, Wp_err, bp_err, We, wsf, wsu);
    fused_main<<<dim3(B_TOT / ROWS), dim3(256), 0, stream>>>(
        ecc, err, ehr, wsf, wsu, Wa, ba, be, Wf2, bf2, out);
}